// Round 1
// baseline (534.977 us; speedup 1.0000x reference)
//
#include <hip/hip_runtime.h>
#include <hip/hip_bf16.h>
#include <math.h>

// Problem constants
#define NSPK  65536
#define HID   1024
#define DUP   2048
#define CAT   3072
#define LN_EPS 1e-5f

// K1 configuration: 512 blocks x 256 threads = 2048 waves, 32 rows/wave.
constexpr int K1_NBLK = 512;

// Workspace layout (floats):
//   query:   [0,     1024)
//   context: [1024,  2048)
//   h:       [2048,  4096)
//   o:       [4096,  5120)
//   pm:      [5120,  5632)   per-block softmax max
//   pl:      [5632,  6144)   per-block softmax denom
//   pc:      [6144,  6144 + 512*1024)  per-block context partials (2 MiB)
#define WS_QUERY   0
#define WS_CONTEXT 1024
#define WS_H       2048
#define WS_O       4096
#define WS_PM      5120
#define WS_PL      5632
#define WS_PC      6144

__device__ __forceinline__ float wave_sum64(float d) {
#pragma unroll
  for (int s = 32; s > 0; s >>= 1) d += __shfl_xor(d, s, 64);
  return d;
}

// ---------------------------------------------------------------------------
// K0: query = W_attn @ u_t.  One wave per output row (1024 rows).
// grid 256 x 256 threads.
__global__ __launch_bounds__(256) void k0_query(
    const float* __restrict__ W_attn, const float* __restrict__ u_t,
    float* __restrict__ query) {
  const int lane = threadIdx.x & 63;
  const int wv = threadIdx.x >> 6;
  const int row = blockIdx.x * 4 + wv;
  const float* rp = W_attn + (size_t)row * HID;
  float d = 0.f;
#pragma unroll
  for (int i = 0; i < 4; ++i) {
    float4 v = *(const float4*)(rp + i * 256 + lane * 4);
    float4 u = *(const float4*)(u_t + i * 256 + lane * 4);
    d += v.x * u.x + v.y * u.y + v.z * u.z + v.w * u.w;
  }
  d = wave_sum64(d);
  if (lane == 0) query[row] = d;
}

// ---------------------------------------------------------------------------
// K1: fused pass over the speaker bank.
//  - copies every row to d_out
//  - computes logit = row . query
//  - online-softmax accumulates context partials
// One wave owns 32 contiguous rows. Block-level combine -> per-block partial.
__global__ __launch_bounds__(256) void k1_pass(
    const float* __restrict__ emb, const float* __restrict__ query,
    float* __restrict__ out, float* __restrict__ pm, float* __restrict__ pl,
    float* __restrict__ pc) {
  const int tid = threadIdx.x;
  const int lane = tid & 63;
  const int wv = tid >> 6;                    // 0..3
  const int gw = blockIdx.x * 4 + wv;         // 0..2047
  const int col = lane * 4;                   // base column within a 256-chunk

  // Preload this lane's query fragment (16 floats).
  float4 q0 = *(const float4*)(query + 0 * 256 + col);
  float4 q1 = *(const float4*)(query + 1 * 256 + col);
  float4 q2 = *(const float4*)(query + 2 * 256 + col);
  float4 q3 = *(const float4*)(query + 3 * 256 + col);

  float m = -INFINITY, l = 0.f;
  float4 c0 = {0.f, 0.f, 0.f, 0.f}, c1 = c0, c2 = c0, c3 = c0;

  const int row0 = gw * 32;
  for (int r = 0; r < 32; ++r) {
    const size_t base = (size_t)(row0 + r) * HID;
    const float* rp = emb + base;
    float4 v0 = *(const float4*)(rp + 0 * 256 + col);
    float4 v1 = *(const float4*)(rp + 1 * 256 + col);
    float4 v2 = *(const float4*)(rp + 2 * 256 + col);
    float4 v3 = *(const float4*)(rp + 3 * 256 + col);
    // copy to output
    float* op = out + base;
    *(float4*)(op + 0 * 256 + col) = v0;
    *(float4*)(op + 1 * 256 + col) = v1;
    *(float4*)(op + 2 * 256 + col) = v2;
    *(float4*)(op + 3 * 256 + col) = v3;
    // dot with query
    float d = v0.x * q0.x + v0.y * q0.y + v0.z * q0.z + v0.w * q0.w +
              v1.x * q1.x + v1.y * q1.y + v1.z * q1.z + v1.w * q1.w +
              v2.x * q2.x + v2.y * q2.y + v2.z * q2.z + v2.w * q2.w +
              v3.x * q3.x + v3.y * q3.y + v3.z * q3.z + v3.w * q3.w;
    d = wave_sum64(d);
    // online softmax update
    float mn = fmaxf(m, d);
    float alpha = __expf(m - mn);   // m=-inf first iter -> alpha=0
    float w = __expf(d - mn);
    l = l * alpha + w;
    c0.x = c0.x * alpha + w * v0.x; c0.y = c0.y * alpha + w * v0.y;
    c0.z = c0.z * alpha + w * v0.z; c0.w = c0.w * alpha + w * v0.w;
    c1.x = c1.x * alpha + w * v1.x; c1.y = c1.y * alpha + w * v1.y;
    c1.z = c1.z * alpha + w * v1.z; c1.w = c1.w * alpha + w * v1.w;
    c2.x = c2.x * alpha + w * v2.x; c2.y = c2.y * alpha + w * v2.y;
    c2.z = c2.z * alpha + w * v2.z; c2.w = c2.w * alpha + w * v2.w;
    c3.x = c3.x * alpha + w * v3.x; c3.y = c3.y * alpha + w * v3.y;
    c3.z = c3.z * alpha + w * v3.z; c3.w = c3.w * alpha + w * v3.w;
    m = mn;
  }

  // Block combine across the 4 waves in LDS.
  __shared__ float sm[4], sl[4];
  __shared__ float sc[4][HID];
  if (lane == 0) { sm[wv] = m; sl[wv] = l; }
  *(float4*)(&sc[wv][0 * 256 + col]) = c0;
  *(float4*)(&sc[wv][1 * 256 + col]) = c1;
  *(float4*)(&sc[wv][2 * 256 + col]) = c2;
  *(float4*)(&sc[wv][3 * 256 + col]) = c3;
  __syncthreads();

  float M = fmaxf(fmaxf(sm[0], sm[1]), fmaxf(sm[2], sm[3]));
  float w0 = __expf(sm[0] - M), w1 = __expf(sm[1] - M);
  float w2 = __expf(sm[2] - M), w3 = __expf(sm[3] - M);

  // each thread combines 4 columns
  const int cc = tid * 4;
  float4 a;
  a.x = w0 * sc[0][cc + 0] + w1 * sc[1][cc + 0] + w2 * sc[2][cc + 0] + w3 * sc[3][cc + 0];
  a.y = w0 * sc[0][cc + 1] + w1 * sc[1][cc + 1] + w2 * sc[2][cc + 1] + w3 * sc[3][cc + 1];
  a.z = w0 * sc[0][cc + 2] + w1 * sc[1][cc + 2] + w2 * sc[2][cc + 2] + w3 * sc[3][cc + 2];
  a.w = w0 * sc[0][cc + 3] + w1 * sc[1][cc + 3] + w2 * sc[2][cc + 3] + w3 * sc[3][cc + 3];
  *(float4*)(pc + (size_t)blockIdx.x * HID + cc) = a;
  if (tid == 0) {
    pm[blockIdx.x] = M;
    pl[blockIdx.x] = w0 * sl[0] + w1 * sl[1] + w2 * sl[2] + w3 * sl[3];
  }
}

// ---------------------------------------------------------------------------
// K2: reduce 512 block partials -> context[1024].
// grid 16 x 256 threads; block b handles 64 columns [64b, 64b+64).
__global__ __launch_bounds__(256) void k2_reduce(
    const float* __restrict__ pm, const float* __restrict__ pl,
    const float* __restrict__ pc, float* __restrict__ context) {
  __shared__ float red[256];
  const int tid = threadIdx.x;
  const int lane = tid & 63;
  const int wv = tid >> 6;

  // global max M (redundant per block; 512 values)
  float mx = -INFINITY;
  for (int p = tid; p < K1_NBLK; p += 256) mx = fmaxf(mx, pm[p]);
  red[tid] = mx;
  __syncthreads();
  for (int s = 128; s > 0; s >>= 1) {
    if (tid < s) red[tid] = fmaxf(red[tid], red[tid + s]);
    __syncthreads();
  }
  const float M = red[0];
  __syncthreads();

  // global denom L
  float ls = 0.f;
  for (int p = tid; p < K1_NBLK; p += 256) ls += __expf(pm[p] - M) * pl[p];
  red[tid] = ls;
  __syncthreads();
  for (int s = 128; s > 0; s >>= 1) {
    if (tid < s) red[tid] += red[tid + s];
    __syncthreads();
  }
  const float L = red[0];
  __syncthreads();

  // column accumulation: wave wv takes partials p = wv, wv+4, ...
  const int c0 = blockIdx.x * 64;
  float acc = 0.f;
  for (int p = wv; p < K1_NBLK; p += 4) {
    float w = __expf(pm[p] - M);
    acc += w * pc[(size_t)p * HID + c0 + lane];
  }
  __shared__ float sc2[4][64];
  sc2[wv][lane] = acc;
  __syncthreads();
  if (tid < 64) {
    float s = sc2[0][tid] + sc2[1][tid] + sc2[2][tid] + sc2[3][tid];
    context[c0 + tid] = s / L;
  }
}

// ---------------------------------------------------------------------------
// K3: h = gelu(W1 @ [u_t | h_s | context] + b1).  One wave per row (2048).
// grid 512 x 256 threads.
__global__ __launch_bounds__(256) void k3_fc1(
    const float* __restrict__ W1, const float* __restrict__ b1,
    const float* __restrict__ u_t, const float* __restrict__ emb,
    const int* __restrict__ s_i_p, const float* __restrict__ context,
    float* __restrict__ h) {
  const int lane = threadIdx.x & 63;
  const int wv = threadIdx.x >> 6;
  const int row = blockIdx.x * 4 + wv;  // 0..2047
  const float* rp = W1 + (size_t)row * CAT;
  const int s_i = *s_i_p;
  const float* hs = emb + (size_t)s_i * HID;
  float d = 0.f;
#pragma unroll
  for (int i = 0; i < 12; ++i) {
    const int k = i * 256 + lane * 4;
    float4 v = *(const float4*)(rp + k);
    const float* src = (i < 4) ? (u_t + k) : (i < 8) ? (hs + k - 1024)
                                                     : (context + k - 2048);
    float4 u = *(const float4*)src;
    d += v.x * u.x + v.y * u.y + v.z * u.z + v.w * u.w;
  }
  d = wave_sum64(d);
  if (lane == 0) {
    float x = d + b1[row];
    // exact GELU: x * 0.5 * (1 + erf(x / sqrt(2)))
    h[row] = 0.5f * x * (1.0f + erff(x * 0.70710678118654752f));
  }
}

// ---------------------------------------------------------------------------
// K4: o = W2 @ h + b2.  One wave per row (1024). grid 256 x 256 threads.
__global__ __launch_bounds__(256) void k4_fc2(
    const float* __restrict__ W2, const float* __restrict__ b2,
    const float* __restrict__ h, float* __restrict__ o) {
  const int lane = threadIdx.x & 63;
  const int wv = threadIdx.x >> 6;
  const int row = blockIdx.x * 4 + wv;
  const float* rp = W2 + (size_t)row * DUP;
  float d = 0.f;
#pragma unroll
  for (int i = 0; i < 8; ++i) {
    const int k = i * 256 + lane * 4;
    float4 v = *(const float4*)(rp + k);
    float4 u = *(const float4*)(h + k);
    d += v.x * u.x + v.y * u.y + v.z * u.z + v.w * u.w;
  }
  d = wave_sum64(d);
  if (lane == 0) o[row] = d + b2[row];
}

// ---------------------------------------------------------------------------
// K5: LayerNorm(o) + residual scatter of row s_i. 1 block x 256 threads.
__global__ __launch_bounds__(256) void k5_ln_scatter(
    const float* __restrict__ o, const float* __restrict__ gamma,
    const float* __restrict__ beta, const float* __restrict__ emb,
    const int* __restrict__ s_i_p, float* __restrict__ out) {
  __shared__ float red[256];
  const int tid = threadIdx.x;
  float4 v = *(const float4*)(o + tid * 4);
  float s = v.x + v.y + v.z + v.w;
  red[tid] = s;
  __syncthreads();
  for (int t = 128; t > 0; t >>= 1) {
    if (tid < t) red[tid] += red[tid + t];
    __syncthreads();
  }
  const float mu = red[0] * (1.0f / HID);
  __syncthreads();
  float dx = v.x - mu, dy = v.y - mu, dz = v.z - mu, dw = v.w - mu;
  red[tid] = dx * dx + dy * dy + dz * dz + dw * dw;
  __syncthreads();
  for (int t = 128; t > 0; t >>= 1) {
    if (tid < t) red[tid] += red[tid + t];
    __syncthreads();
  }
  const float var = red[0] * (1.0f / HID);
  const float inv = rsqrtf(var + LN_EPS);
  const int s_i = *s_i_p;
  const float* hs = emb + (size_t)s_i * HID;
  float4 g = *(const float4*)(gamma + tid * 4);
  float4 b = *(const float4*)(beta + tid * 4);
  float4 hv = *(const float4*)(hs + tid * 4);
  float4 r;
  r.x = hv.x + dx * inv * g.x + b.x;
  r.y = hv.y + dy * inv * g.y + b.y;
  r.z = hv.z + dz * inv * g.z + b.z;
  r.w = hv.w + dw * inv * g.w + b.w;
  *(float4*)(out + (size_t)s_i * HID + tid * 4) = r;
}

// ---------------------------------------------------------------------------
extern "C" void kernel_launch(void* const* d_in, const int* in_sizes, int n_in,
                              void* d_out, int out_size, void* d_ws, size_t ws_size,
                              hipStream_t stream) {
  const float* u_t     = (const float*)d_in[0];
  const float* emb     = (const float*)d_in[1];
  const float* W_attn  = (const float*)d_in[2];
  const float* W1      = (const float*)d_in[3];
  const float* b1      = (const float*)d_in[4];
  const float* W2      = (const float*)d_in[5];
  const float* b2      = (const float*)d_in[6];
  const float* gamma   = (const float*)d_in[7];
  const float* beta    = (const float*)d_in[8];
  const int*   s_i_p   = (const int*)d_in[9];
  float* out = (float*)d_out;

  float* ws = (float*)d_ws;
  float* query   = ws + WS_QUERY;
  float* context = ws + WS_CONTEXT;
  float* h       = ws + WS_H;
  float* o       = ws + WS_O;
  float* pm      = ws + WS_PM;
  float* pl      = ws + WS_PL;
  float* pc      = ws + WS_PC;

  k0_query<<<256, 256, 0, stream>>>(W_attn, u_t, query);
  k1_pass<<<K1_NBLK, 256, 0, stream>>>(emb, query, out, pm, pl, pc);
  k2_reduce<<<16, 256, 0, stream>>>(pm, pl, pc, context);
  k3_fc1<<<512, 256, 0, stream>>>(W1, b1, u_t, emb, s_i_p, context, h);
  k4_fc2<<<256, 256, 0, stream>>>(W2, b2, h, o);
  k5_ln_scatter<<<1, 256, 0, stream>>>(o, gamma, beta, emb, s_i_p, out);
}